// Round 4
// baseline (415.068 us; speedup 1.0000x reference)
//
#include <hip/hip_runtime.h>
#include <math.h>

#define C_DIM 96
#define CR 24
#define H_DIM 128
#define W_DIM 128
#define B_DIM 32
#define N_PLANES (B_DIM * C_DIM)      // 3072
#define RPC 16                        // rows per chunk (8 chunks x 16 rows = 128)

// ---------------- Kernel 1: adaptive avg pool (per-plane mean) ----------------
// (byte-identical to the verified baseline version)
__global__ void pool_kernel(const float* __restrict__ x, float* __restrict__ pooled) {
    int plane = blockIdx.x;                       // b*96 + c, 3072 planes
    const float4* xp = (const float4*)(x + (size_t)plane * (H_DIM * W_DIM));
    float s = 0.f;
    for (int i = threadIdx.x; i < 4096; i += 256) {
        float4 v = xp[i];
        s += v.x + v.y + v.z + v.w;
    }
    for (int off = 32; off; off >>= 1) s += __shfl_down(s, off, 64);
    __shared__ float ls[4];
    int lane = threadIdx.x & 63, wv = threadIdx.x >> 6;
    if (lane == 0) ls[wv] = s;
    __syncthreads();
    if (threadIdx.x == 0) {
        float t = ls[0] + ls[1] + ls[2] + ls[3];
        pooled[plane] = t * (1.f / (H_DIM * W_DIM));
    }
}

// ---------------- Kernel 2: fused dynamic-weight MLP + per-sample depthwise 3x3 ----------------
// Regrid vs round 3: ONE PLANE PER BLOCK (3072 blocks), 8 chunks x 16 rows/thread.
//   -> 8 blocks/CU (full 32 waves/CU, was 24) and per-thread serial chain 32->16.
//   Theory: conv is latency-bound (round-1 evidence: 3 blocks/CU nearly doubled time).
// Inner loop idiom identical to verified round 3: shuffles UNCONDITIONAL, edge
// select after (ds_bpermute returns 0 for exec-masked lanes).
__global__ void __launch_bounds__(256, 8) fused_dwconv_kernel(const float* __restrict__ x,
                                                              const float* __restrict__ pooled,
                                                              const float* __restrict__ w1,
                                                              const float* __restrict__ gamma,
                                                              const float* __restrict__ beta,
                                                              const float* __restrict__ rmean,
                                                              const float* __restrict__ rvar,
                                                              const float* __restrict__ w2,
                                                              const float* __restrict__ b2,
                                                              const float* __restrict__ bias,
                                                              float* __restrict__ out) {
    int tid = threadIdx.x;
    int plane = blockIdx.x;                 // b*96 + c
    int b = plane / C_DIM;
    int c0 = plane % C_DIM;

    // thread map: g = col group (float4), chunk = row chunk (0..7)
    int g = tid & 31;
    int chunk = tid >> 5;
    int col = g << 2;
    int r0 = chunk * RPC;

    const float* xp = x + (size_t)plane * (H_DIM * W_DIM);
    float* op = out + (size_t)plane * (H_DIM * W_DIM);

    // ---- issue prologue row loads EARLY (latency hides under the MLP) ----
    float4 pvr; pvr.x = pvr.y = pvr.z = pvr.w = 0.f;
    if (r0 > 0) pvr = *(const float4*)(xp + (r0 - 1) * W_DIM + col);
    float4 cvr = *(const float4*)(xp + r0 * W_DIM + col);
    float4 nvr = *(const float4*)(xp + (r0 + 1) * W_DIM + col);   // r0+1 <= 113, always valid

    __shared__ float pl[C_DIM];
    __shared__ float h1[CR];
    __shared__ float wsm[10];               // 9 taps + bias for this plane's channel

    if (tid < C_DIM) pl[tid] = pooled[b * C_DIM + tid];
    __syncthreads();
    if (tid < CR) {
        float s = 0.f;
        const float* wr = w1 + tid * C_DIM;
        #pragma unroll 8
        for (int c = 0; c < C_DIM; c++) s += pl[c] * wr[c];
        s = (s - rmean[tid]) * rsqrtf(rvar[tid] + 1e-5f) * gamma[tid] + beta[tid];
        h1[tid] = 1.f / (1.f + expf(-s));
    }
    __syncthreads();
    if (tid < 10) {
        if (tid < 9) {
            int row = c0 * 9 + tid;         // wdyn flat index within batch
            float s = b2[row];
            const float* wr = w2 + row * CR;
            #pragma unroll
            for (int j = 0; j < CR; j++) s += h1[j] * wr[j];
            wsm[tid] = s;
        } else {
            wsm[9] = bias[c0];
        }
    }
    __syncthreads();

    float w00 = wsm[0], w01 = wsm[1], w02 = wsm[2];
    float w10 = wsm[3], w11 = wsm[4], w12 = wsm[5];
    float w20 = wsm[6], w21 = wsm[7], w22 = wsm[8];
    float bb = wsm[9];
    const bool leftEdge = (g == 0), rightEdge = (g == 31);

    // halos for the three prologue rows — shuffles UNCONDITIONAL, select after
    float4 pv = pvr, cv = cvr, nv = nvr;
    float t0 = __shfl_up(pvr.w, 1, 64);
    float t1 = __shfl_down(pvr.x, 1, 64);
    float t2 = __shfl_up(cvr.w, 1, 64);
    float t3 = __shfl_down(cvr.x, 1, 64);
    float t4 = __shfl_up(nvr.w, 1, 64);
    float t5 = __shfl_down(nvr.x, 1, 64);
    float plh = leftEdge ? 0.f : t0;
    float prh = rightEdge ? 0.f : t1;
    float clh = leftEdge ? 0.f : t2;
    float crh = rightEdge ? 0.f : t3;
    float nlh = leftEdge ? 0.f : t4;
    float nrh = rightEdge ? 0.f : t5;

#define COMPUTE_STORE(ROW)                                                   \
    {                                                                        \
        float4 o;                                                            \
        o.x = w00 * plh  + w01 * pv.x + w02 * pv.y                           \
            + w10 * clh  + w11 * cv.x + w12 * cv.y                           \
            + w20 * nlh  + w21 * nv.x + w22 * nv.y + bb;                     \
        o.y = w00 * pv.x + w01 * pv.y + w02 * pv.z                           \
            + w10 * cv.x + w11 * cv.y + w12 * cv.z                           \
            + w20 * nv.x + w21 * nv.y + w22 * nv.z + bb;                     \
        o.z = w00 * pv.y + w01 * pv.z + w02 * pv.w                           \
            + w10 * cv.y + w11 * cv.z + w12 * cv.w                           \
            + w20 * nv.y + w21 * nv.z + w22 * nv.w + bb;                     \
        o.w = w00 * pv.z + w01 * pv.w + w02 * prh                            \
            + w10 * cv.z + w11 * cv.w + w12 * crh                            \
            + w20 * nv.z + w21 * nv.w + w22 * nrh + bb;                      \
        *(float4*)(op + (ROW) * W_DIM + col) = o;                            \
    }

#define SHIFT_IN(V, L, R)                                                    \
    pv = cv; plh = clh; prh = crh;                                           \
    cv = nv; clh = nlh; crh = nrh;                                           \
    nv = (V); nlh = (L); nrh = (R);

    // steady state: compute rows r0 .. r0+13; load rows r0+2 .. r0+15 (always in-plane)
    #pragma unroll 7
    for (int i = 0; i < RPC - 2; ++i) {
        int r = r0 + i;
        float4 v = *(const float4*)(xp + (r + 2) * W_DIM + col);
        float l = __shfl_up(v.w, 1, 64);
        float rr = __shfl_down(v.x, 1, 64);
        COMPUTE_STORE(r);
        SHIFT_IN(v, leftEdge ? 0.f : l, rightEdge ? 0.f : rr);
    }
    // peeled iter 14: load row r0+16 (invalid only for chunk 7)
    {
        int r = r0 + RPC - 2;
        float4 v; v.x = v.y = v.z = v.w = 0.f;
        if (r + 2 < H_DIM) v = *(const float4*)(xp + (r + 2) * W_DIM + col);
        float l = __shfl_up(v.w, 1, 64);
        float rr = __shfl_down(v.x, 1, 64);
        COMPUTE_STORE(r);
        SHIFT_IN(v, leftEdge ? 0.f : l, rightEdge ? 0.f : rr);
    }
    // peeled iter 15: no further load
    {
        int r = r0 + RPC - 1;
        COMPUTE_STORE(r);
    }
#undef COMPUTE_STORE
#undef SHIFT_IN
}

extern "C" void kernel_launch(void* const* d_in, const int* in_sizes, int n_in,
                              void* d_out, int out_size, void* d_ws, size_t ws_size,
                              hipStream_t stream) {
    const float* x     = (const float*)d_in[0];
    const float* w1    = (const float*)d_in[1];
    const float* gamma = (const float*)d_in[2];
    const float* beta  = (const float*)d_in[3];
    const float* rmean = (const float*)d_in[4];
    const float* rvar  = (const float*)d_in[5];
    const float* w2    = (const float*)d_in[6];
    const float* b2    = (const float*)d_in[7];
    const float* bias  = (const float*)d_in[8];
    float* out = (float*)d_out;

    float* pooled = (float*)d_ws;                           // 3072 floats

    pool_kernel<<<N_PLANES, 256, 0, stream>>>(x, pooled);
    fused_dwconv_kernel<<<N_PLANES, 256, 0, stream>>>(
        x, pooled, w1, gamma, beta, rmean, rvar, w2, b2, bias, out);
}